// Round 1
// baseline (634.979 us; speedup 1.0000x reference)
//
#include <hip/hip_runtime.h>
#include <math.h>

#define NFFT      512
#define HOP       256
#define NBINS     257
#define NMELS     64
#define BATCH     32
#define WAVE_LEN  960000
#define NFRAMES   3751
#define CHUNK     128
#define NCHUNK    30                 // ceil(3751/128)
#define MROWS     (BATCH * NFRAMES)  // 120032

__device__ __forceinline__ float sigmoidf_(float x) { return 1.0f / (1.0f + __expf(-x)); }

#define PI2F 6.283185307179586f

// ---------------------------------------------------------------------------
// Kernel 1: STFT magnitude. One wave (64 threads) per (frame, batch).
// DIF radix-2 FFT in LDS: natural-order input, bit-reversed output.
// ---------------------------------------------------------------------------
__global__ __launch_bounds__(64) void stft_kernel(const float* __restrict__ wav,
                                                  float* __restrict__ mag) {
  const int t   = blockIdx.x;   // frame
  const int b   = blockIdx.y;   // batch
  const int tid = threadIdx.x;  // 0..63

  __shared__ float re[NFFT], im[NFFT];
  __shared__ float twc[NFFT / 2], tws[NFFT / 2];

  // twiddles: W_512^k = exp(-2*pi*i*k/512), k = 0..255
#pragma unroll
  for (int j = 0; j < 4; ++j) {
    int k = j * 64 + tid;
    float ang = -PI2F * (float)k / (float)NFFT;
    twc[k] = __cosf(ang);
    tws[k] = __sinf(ang);
  }

  // load 512 samples with reflect padding + Hann window
  const float* w = wav + (size_t)b * WAVE_LEN;
  const int base = t * HOP - (NFFT / 2);
#pragma unroll
  for (int j = 0; j < 8; ++j) {
    int n = j * 64 + tid;
    int pos = base + n;
    pos = (pos < 0) ? -pos : pos;
    pos = (pos >= WAVE_LEN) ? (2 * WAVE_LEN - 2 - pos) : pos;
    float x = w[pos];
    float win = 0.5f - 0.5f * __cosf(PI2F * (float)n / (float)NFFT);
    re[n] = x * win;
    im[n] = 0.0f;
  }
  __syncthreads();

  // 9 DIF radix-2 stages
  for (int s = 9; s >= 1; --s) {
    const int half = 1 << (s - 1);
#pragma unroll
    for (int jj = 0; jj < 4; ++jj) {
      int j = jj * 64 + tid;           // butterfly id 0..255
      int g = j >> (s - 1);
      int p = j & (half - 1);
      int i0 = (g << s) + p;
      int i1 = i0 + half;
      float ur = re[i0], ui = im[i0];
      float vr = re[i1], vi = im[i1];
      float sr = ur - vr, si = ui - vi;
      re[i0] = ur + vr;
      im[i0] = ui + vi;
      int tw = p << (9 - s);
      float wc = twc[tw], ws = tws[tw];
      re[i1] = sr * wc - si * ws;
      im[i1] = si * wc + sr * ws;
    }
    __syncthreads();
  }

  // magnitudes for bins 0..256; FFT result for bin k sits at bit-reversed index
  float* out = mag + ((size_t)b * NFRAMES + t) * NBINS;
  for (int k = tid; k < NBINS; k += 64) {
    int idx = (int)(__brev((unsigned)k) >> 23);  // 9-bit reverse
    float r = re[idx], i = im[idx];
    out[k] = sqrtf(r * r + i * i);
  }
}

// ---------------------------------------------------------------------------
// Kernel 2: chunked scan, phase 1 — per-chunk partial (zero-carry) EMA sums.
// One thread per (b, f, chunk).
// ---------------------------------------------------------------------------
__global__ void scan_partial(const float* __restrict__ mag,
                             const float* __restrict__ alpha,
                             float* __restrict__ Bc) {
  const int c = blockIdx.x, b = blockIdx.y, f = threadIdx.x;
  if (f >= NBINS) return;
  const float a = sigmoidf_(alpha[f]);
  const float om = 1.0f - a;
  const int t0 = c * CHUNK;
  const int t1 = min(NFRAMES, t0 + CHUNK);
  const float* p = mag + ((size_t)b * NFRAMES + t0) * NBINS + f;
  float v = 0.0f;
  for (int t = t0; t < t1; ++t) {
    v = fmaf(a, v, om * (*p));
    p += NBINS;
  }
  Bc[((size_t)b * NBINS + f) * NCHUNK + c] = v;
}

// ---------------------------------------------------------------------------
// Kernel 3: phase 2 — propagate carries across chunks. carry init = mag[b,0,f].
// avg_end(chunk c) = a^128 * carry_in(c) + B_c ; carry_in(c+1) = avg_end(c).
// ---------------------------------------------------------------------------
__global__ void scan_combine(const float* __restrict__ mag,
                             const float* __restrict__ alpha,
                             const float* __restrict__ Bc,
                             float* __restrict__ carry) {
  const int b = blockIdx.x, f = threadIdx.x;
  if (f >= NBINS) return;
  const float a = sigmoidf_(alpha[f]);
  float aL = a;  // a^128 via 7 squarings (all full chunks have length 128)
#pragma unroll
  for (int i = 0; i < 7; ++i) aL *= aL;
  float v = mag[(size_t)b * NFRAMES * NBINS + f];  // scan's initial carry
  const size_t off = ((size_t)b * NBINS + f) * NCHUNK;
  for (int c = 0; c < NCHUNK; ++c) {
    carry[off + c] = v;
    v = fmaf(aL, v, Bc[off + c]);  // aL wrong for the (short) last chunk, but unused
  }
}

// ---------------------------------------------------------------------------
// Kernel 4: phase 3 — redo local scan with true carry, write norm in place.
// ---------------------------------------------------------------------------
__global__ void scan_apply(float* __restrict__ mag,
                           const float* __restrict__ alpha,
                           const float* __restrict__ carry) {
  const int c = blockIdx.x, b = blockIdx.y, f = threadIdx.x;
  if (f >= NBINS) return;
  const float a = sigmoidf_(alpha[f]);
  const float om = 1.0f - a;
  float v = carry[((size_t)b * NBINS + f) * NCHUNK + c];
  const int t0 = c * CHUNK;
  const int t1 = min(NFRAMES, t0 + CHUNK);
  float* p = mag + ((size_t)b * NFRAMES + t0) * NBINS + f;
  for (int t = t0; t < t1; ++t) {
    float m = *p;
    v = fmaf(a, v, om * m);
    *p = m / (v + 1e-8f);
    p += NBINS;
  }
}

// ---------------------------------------------------------------------------
// Kernel 5: mel projection GEMM. C(120032x64) = A(120032x257) @ B(257x64) +1e-6
// 64x64 output tile per block, 4x4 register blocking, fp32 vector ALU.
// ---------------------------------------------------------------------------
__global__ __launch_bounds__(256) void mel_gemm(const float* __restrict__ A,
                                                const float* __restrict__ Bm,
                                                float* __restrict__ C) {
  __shared__ float As[64][65];  // +1 pad: conflict-free column reads
  __shared__ float Bs[64][64];
  const int row0 = blockIdx.x * 64;
  const int tid = threadIdx.x;
  const int ty = tid >> 4, tx = tid & 15;
  float acc[4][4] = {};

  for (int kt = 0; kt < NBINS; kt += 64) {
    const int kmax = min(64, NBINS - kt);
#pragma unroll 4
    for (int i = tid; i < 64 * 64; i += 256) {
      int r = i >> 6, k = i & 63;
      int row = row0 + r;
      As[r][k] = (row < MROWS && k < kmax) ? A[(size_t)row * NBINS + kt + k] : 0.0f;
    }
#pragma unroll 4
    for (int i = tid; i < 64 * 64; i += 256) {
      int k = i >> 6, m = i & 63;
      Bs[k][m] = (k < kmax) ? Bm[(kt + k) * NMELS + m] : 0.0f;
    }
    __syncthreads();
#pragma unroll 8
    for (int k = 0; k < 64; ++k) {
      float av[4], bv[4];
#pragma unroll
      for (int i = 0; i < 4; ++i) av[i] = As[ty * 4 + i][k];
#pragma unroll
      for (int j = 0; j < 4; ++j) bv[j] = Bs[k][tx * 4 + j];
#pragma unroll
      for (int i = 0; i < 4; ++i)
#pragma unroll
        for (int j = 0; j < 4; ++j) acc[i][j] = fmaf(av[i], bv[j], acc[i][j]);
    }
    __syncthreads();
  }

#pragma unroll
  for (int i = 0; i < 4; ++i) {
    int row = row0 + ty * 4 + i;
    if (row < MROWS) {
#pragma unroll
      for (int j = 0; j < 4; ++j)
        C[(size_t)row * NMELS + tx * 4 + j] = acc[i][j] + 1e-6f;
    }
  }
}

// ---------------------------------------------------------------------------
extern "C" void kernel_launch(void* const* d_in, const int* in_sizes, int n_in,
                              void* d_out, int out_size, void* d_ws, size_t ws_size,
                              hipStream_t stream) {
  const float* wav   = (const float*)d_in[0];  // (32, 960000) fp32
  const float* alpha = (const float*)d_in[1];  // (1, 257) fp32
  const float* mel   = (const float*)d_in[2];  // (257, 64) fp32
  float* out = (float*)d_out;                  // (32, 3751, 64) fp32

  // workspace layout
  float* mag   = (float*)d_ws;                               // 32*3751*257 fp32 (mag -> norm in place)
  float* Bc    = mag + (size_t)BATCH * NFRAMES * NBINS;      // 32*257*30
  float* carry = Bc + (size_t)BATCH * NBINS * NCHUNK;        // 32*257*30

  stft_kernel<<<dim3(NFRAMES, BATCH), 64, 0, stream>>>(wav, mag);
  scan_partial<<<dim3(NCHUNK, BATCH), 320, 0, stream>>>(mag, alpha, Bc);
  scan_combine<<<BATCH, 320, 0, stream>>>(mag, alpha, Bc, carry);
  scan_apply<<<dim3(NCHUNK, BATCH), 320, 0, stream>>>(mag, alpha, carry);
  mel_gemm<<<(MROWS + 63) / 64, 256, 0, stream>>>(mag, mel, out);
}

// Round 2
// 432.131 us; speedup vs baseline: 1.4694x; 1.4694x over previous
//
#include <hip/hip_runtime.h>
#include <math.h>

#define NFFT      512
#define HOP       256
#define NBINS     257
#define NMELS     64
#define BATCH     32
#define WAVE_LEN  960000
#define NFRAMES   3751
#define NPAIRS    1876               // ceil(3751/2)
#define CHUNK     128
#define NCHUNK    30                 // ceil(3751/128)
#define MROWS     (BATCH * NFRAMES)  // 120032

#define PI2F 6.283185307179586f

__device__ __forceinline__ float sigmoidf_(float x) { return 1.0f / (1.0f + __expf(-x)); }

// ---------------------------------------------------------------------------
// Kernel 0: fill window + twiddle tables (once per launch; ws is re-poisoned).
// win[n] = hann(n); twA[j*64+p] = W_512^{p*j} (interleaved c,s); twB[p*8+j] = W_64^{p*j}
// ---------------------------------------------------------------------------
__global__ __launch_bounds__(512) void init_tables(float* __restrict__ win,
                                                   float* __restrict__ twA,
                                                   float* __restrict__ twB) {
  const int n = threadIdx.x;
  win[n] = 0.5f - 0.5f * __cosf(PI2F * (float)n / (float)NFFT);
  {
    int j = n >> 6, p = n & 63;
    float ang = -PI2F * (float)(p * j) / 512.0f;
    twA[2 * n]     = __cosf(ang);
    twA[2 * n + 1] = __sinf(ang);
  }
  if (n < 64) {
    int p = n >> 3, j = n & 7;
    float ang = -PI2F * (float)(p * j) / 64.0f;
    twB[2 * n]     = __cosf(ang);
    twB[2 * n + 1] = __sinf(ang);
  }
}

// 8-point DFT, natural-order in/out, DIT from two FFT4s.
__device__ __forceinline__ void fft8(float zr[8], float zi[8]) {
  float er[4], ei[4], orr[4], oi[4];
  {
    float Ar = zr[0] + zr[4], Ai = zi[0] + zi[4];
    float Br = zr[2] + zr[6], Bi = zi[2] + zi[6];
    float Cr = zr[0] - zr[4], Ci = zi[0] - zi[4];
    float dr = zr[2] - zr[6], di = zi[2] - zi[6];
    er[0] = Ar + Br; ei[0] = Ai + Bi;
    er[1] = Cr + di; ei[1] = Ci - dr;   // C + (-i)d
    er[2] = Ar - Br; ei[2] = Ai - Bi;
    er[3] = Cr - di; ei[3] = Ci + dr;
  }
  {
    float Ar = zr[1] + zr[5], Ai = zi[1] + zi[5];
    float Br = zr[3] + zr[7], Bi = zi[3] + zi[7];
    float Cr = zr[1] - zr[5], Ci = zi[1] - zi[5];
    float dr = zr[3] - zr[7], di = zi[3] - zi[7];
    orr[0] = Ar + Br; oi[0] = Ai + Bi;
    orr[1] = Cr + di; oi[1] = Ci - dr;
    orr[2] = Ar - Br; oi[2] = Ai - Bi;
    orr[3] = Cr - di; oi[3] = Ci + dr;
  }
  const float R = 0.70710678118654752f;
  zr[0] = er[0] + orr[0]; zi[0] = ei[0] + oi[0];
  zr[4] = er[0] - orr[0]; zi[4] = ei[0] - oi[0];
  { // j=1: W8 = R*(1-i)
    float tr = R * (orr[1] + oi[1]);
    float ti = R * (oi[1] - orr[1]);
    zr[1] = er[1] + tr; zi[1] = ei[1] + ti;
    zr[5] = er[1] - tr; zi[5] = ei[1] - ti;
  }
  { // j=2: W8^2 = -i
    float tr = oi[2], ti = -orr[2];
    zr[2] = er[2] + tr; zi[2] = ei[2] + ti;
    zr[6] = er[2] - tr; zi[6] = ei[2] - ti;
  }
  { // j=3: W8^3 = -R*(1+i)
    float tr = R * (oi[3] - orr[3]);
    float ti = -R * (orr[3] + oi[3]);
    zr[3] = er[3] + tr; zi[3] = ei[3] + ti;
    zr[7] = er[3] - tr; zi[7] = ei[3] - ti;
  }
}

// ---------------------------------------------------------------------------
// Kernel 1: STFT magnitude. One wave per FRAME-PAIR: frames (2p, 2p+1) packed
// as re/im of one 512-pt complex FFT (radix-8, registers, 2 LDS exchanges).
// LDS exchange addressing uses tau(n) = n + (n>>3): all patterns <=2-way.
// ---------------------------------------------------------------------------
__global__ __launch_bounds__(64) void stft_kernel(const float* __restrict__ wav,
                                                  const float* __restrict__ win,
                                                  const float* __restrict__ twA,
                                                  const float* __restrict__ twB,
                                                  float* __restrict__ mag) {
  const int pr  = blockIdx.x;   // pair index
  const int b   = blockIdx.y;   // batch
  const int tid = threadIdx.x;  // 0..63

  __shared__ float sre[576], sim[576];

  const float* w = wav + (size_t)b * WAVE_LEN;
  const int f0 = 2 * pr, f1 = f0 + 1;
  const bool has1 = (f1 < NFRAMES);
  const int base0 = f0 * HOP - (NFFT / 2);
  const int base1 = base0 + HOP;  // f1 >= 1 -> base1 >= 0; base1+511 < WAVE_LEN always

  float zr[8], zi[8];
#pragma unroll
  for (int j = 0; j < 8; ++j) {
    int n = tid + 64 * j;
    float wn = win[n];
    int p0 = base0 + n;
    p0 = (p0 < 0) ? -p0 : p0;
    p0 = (p0 >= WAVE_LEN) ? (2 * WAVE_LEN - 2 - p0) : p0;
    float x0 = w[p0];
    float x1 = has1 ? w[base1 + n] : 0.0f;
    zr[j] = x0 * wn;
    zi[j] = x1 * wn;
  }

  // ---- stage A: span 64, twiddle W_512^{tid*j}
  fft8(zr, zi);
  const float2* twA2 = (const float2*)twA;
#pragma unroll
  for (int j = 1; j < 8; ++j) {
    float2 t = twA2[j * 64 + tid];
    float r = zr[j] * t.x - zi[j] * t.y;
    zi[j]   = zi[j] * t.x + zr[j] * t.y;
    zr[j]   = r;
  }

  // exchange 1: write n = tid + 64j, read n = g*64 + q + 8j
#pragma unroll
  for (int j = 0; j < 8; ++j) {
    int n = tid + 64 * j;
    int a = n + (n >> 3);
    sre[a] = zr[j]; sim[a] = zi[j];
  }
  __syncthreads();
  const int g = tid >> 3, q = tid & 7;
#pragma unroll
  for (int j = 0; j < 8; ++j) {
    int n = g * 64 + q + 8 * j;
    int a = n + (n >> 3);
    zr[j] = sre[a]; zi[j] = sim[a];
  }

  // ---- stage B: span 8, twiddle W_64^{q*j}
  fft8(zr, zi);
  const float2* twB2 = (const float2*)twB;
#pragma unroll
  for (int j = 1; j < 8; ++j) {
    float2 t = twB2[q * 8 + j];
    float r = zr[j] * t.x - zi[j] * t.y;
    zi[j]   = zi[j] * t.x + zr[j] * t.y;
    zr[j]   = r;
  }

  // exchange 2: write n = g*64 + q + 8j, read n = 8*tid + j
  __syncthreads();
#pragma unroll
  for (int j = 0; j < 8; ++j) {
    int n = g * 64 + q + 8 * j;
    int a = n + (n >> 3);
    sre[a] = zr[j]; sim[a] = zi[j];
  }
  __syncthreads();
#pragma unroll
  for (int j = 0; j < 8; ++j) {
    int n = 8 * tid + j;
    int a = n + (n >> 3);   // = 9*tid + j
    zr[j] = sre[a]; zi[j] = sim[a];
  }

  // ---- stage C: span 1, no twiddle
  fft8(zr, zi);

  // final store at natural bin order: storage idx n=8*tid+j -> bin k = 64j + 8q + g
  __syncthreads();
#pragma unroll
  for (int j = 0; j < 8; ++j) {
    int k = 64 * j + 8 * q + g;
    sre[k] = zr[j]; sim[k] = zi[j];
  }
  __syncthreads();

  // unpack two real spectra + magnitudes
  float* out0 = mag + ((size_t)b * NFRAMES + f0) * NBINS;
  float* out1 = out0 + NBINS;
  for (int k = tid; k <= 256; k += 64) {
    int kn = (NFFT - k) & (NFFT - 1);
    float ar = sre[k],  ai = sim[k];
    float br = sre[kn], bi = sim[kn];
    float xr = ar + br, xi = ai - bi;   // 2*X_frame0
    float yr = ai + bi, yi = ar - br;   // 2*X_frame1 (up to sign of imag)
    out0[k] = 0.5f * sqrtf(xr * xr + xi * xi);
    if (has1) out1[k] = 0.5f * sqrtf(yr * yr + yi * yi);
  }
}

// ---------------------------------------------------------------------------
// Kernel 2: chunked scan, phase 1 — per-chunk partial (zero-carry) EMA sums.
// ---------------------------------------------------------------------------
__global__ void scan_partial(const float* __restrict__ mag,
                             const float* __restrict__ alpha,
                             float* __restrict__ Bc) {
  const int c = blockIdx.x, b = blockIdx.y, f = threadIdx.x;
  if (f >= NBINS) return;
  const float a = sigmoidf_(alpha[f]);
  const float om = 1.0f - a;
  const int t0 = c * CHUNK;
  const int t1 = min(NFRAMES, t0 + CHUNK);
  const float* p = mag + ((size_t)b * NFRAMES + t0) * NBINS + f;
  float v = 0.0f;
  for (int t = t0; t < t1; ++t) {
    v = fmaf(a, v, om * (*p));
    p += NBINS;
  }
  Bc[((size_t)b * NBINS + f) * NCHUNK + c] = v;
}

// ---------------------------------------------------------------------------
// Kernel 3: phase 2 — propagate carries across chunks. carry init = mag[b,0,f].
// ---------------------------------------------------------------------------
__global__ void scan_combine(const float* __restrict__ mag,
                             const float* __restrict__ alpha,
                             const float* __restrict__ Bc,
                             float* __restrict__ carry) {
  const int b = blockIdx.x, f = threadIdx.x;
  if (f >= NBINS) return;
  const float a = sigmoidf_(alpha[f]);
  float aL = a;  // a^128 via 7 squarings
#pragma unroll
  for (int i = 0; i < 7; ++i) aL *= aL;
  float v = mag[(size_t)b * NFRAMES * NBINS + f];
  const size_t off = ((size_t)b * NBINS + f) * NCHUNK;
  for (int c = 0; c < NCHUNK; ++c) {
    carry[off + c] = v;
    v = fmaf(aL, v, Bc[off + c]);
  }
}

// ---------------------------------------------------------------------------
// Kernel 4: phase 3 — redo local scan with true carry, write norm in place.
// ---------------------------------------------------------------------------
__global__ void scan_apply(float* __restrict__ mag,
                           const float* __restrict__ alpha,
                           const float* __restrict__ carry) {
  const int c = blockIdx.x, b = blockIdx.y, f = threadIdx.x;
  if (f >= NBINS) return;
  const float a = sigmoidf_(alpha[f]);
  const float om = 1.0f - a;
  float v = carry[((size_t)b * NBINS + f) * NCHUNK + c];
  const int t0 = c * CHUNK;
  const int t1 = min(NFRAMES, t0 + CHUNK);
  float* p = mag + ((size_t)b * NFRAMES + t0) * NBINS + f;
  for (int t = t0; t < t1; ++t) {
    float m = *p;
    v = fmaf(a, v, om * m);
    *p = m / (v + 1e-8f);
    p += NBINS;
  }
}

// ---------------------------------------------------------------------------
// Kernel 5: mel projection GEMM. C(120032x64) = A(120032x257) @ B(257x64) +1e-6
// ---------------------------------------------------------------------------
__global__ __launch_bounds__(256) void mel_gemm(const float* __restrict__ A,
                                                const float* __restrict__ Bm,
                                                float* __restrict__ C) {
  __shared__ float As[64][65];
  __shared__ float Bs[64][64];
  const int row0 = blockIdx.x * 64;
  const int tid = threadIdx.x;
  const int ty = tid >> 4, tx = tid & 15;
  float acc[4][4] = {};

  for (int kt = 0; kt < NBINS; kt += 64) {
    const int kmax = min(64, NBINS - kt);
#pragma unroll 4
    for (int i = tid; i < 64 * 64; i += 256) {
      int r = i >> 6, k = i & 63;
      int row = row0 + r;
      As[r][k] = (row < MROWS && k < kmax) ? A[(size_t)row * NBINS + kt + k] : 0.0f;
    }
#pragma unroll 4
    for (int i = tid; i < 64 * 64; i += 256) {
      int k = i >> 6, m = i & 63;
      Bs[k][m] = (k < kmax) ? Bm[(kt + k) * NMELS + m] : 0.0f;
    }
    __syncthreads();
#pragma unroll 8
    for (int k = 0; k < 64; ++k) {
      float av[4], bv[4];
#pragma unroll
      for (int i = 0; i < 4; ++i) av[i] = As[ty * 4 + i][k];
#pragma unroll
      for (int j = 0; j < 4; ++j) bv[j] = Bs[k][tx * 4 + j];
#pragma unroll
      for (int i = 0; i < 4; ++i)
#pragma unroll
        for (int j = 0; j < 4; ++j) acc[i][j] = fmaf(av[i], bv[j], acc[i][j]);
    }
    __syncthreads();
  }

#pragma unroll
  for (int i = 0; i < 4; ++i) {
    int row = row0 + ty * 4 + i;
    if (row < MROWS) {
#pragma unroll
      for (int j = 0; j < 4; ++j)
        C[(size_t)row * NMELS + tx * 4 + j] = acc[i][j] + 1e-6f;
    }
  }
}

// ---------------------------------------------------------------------------
extern "C" void kernel_launch(void* const* d_in, const int* in_sizes, int n_in,
                              void* d_out, int out_size, void* d_ws, size_t ws_size,
                              hipStream_t stream) {
  const float* wav   = (const float*)d_in[0];  // (32, 960000) fp32
  const float* alpha = (const float*)d_in[1];  // (1, 257) fp32
  const float* mel   = (const float*)d_in[2];  // (257, 64) fp32
  float* out = (float*)d_out;                  // (32, 3751, 64) fp32

  // workspace layout
  float* mag   = (float*)d_ws;                            // 32*3751*257
  float* Bc    = mag + (size_t)BATCH * NFRAMES * NBINS;   // 32*257*30
  float* carry = Bc + (size_t)BATCH * NBINS * NCHUNK;     // 32*257*30
  float* win   = carry + (size_t)BATCH * NBINS * NCHUNK;  // 512
  float* twA   = win + 512;                               // 1024 (512 c,s pairs)
  float* twB   = twA + 1024;                              // 128  (64 c,s pairs)

  init_tables<<<1, 512, 0, stream>>>(win, twA, twB);
  stft_kernel<<<dim3(NPAIRS, BATCH), 64, 0, stream>>>(wav, win, twA, twB, mag);
  scan_partial<<<dim3(NCHUNK, BATCH), 320, 0, stream>>>(mag, alpha, Bc);
  scan_combine<<<BATCH, 320, 0, stream>>>(mag, alpha, Bc, carry);
  scan_apply<<<dim3(NCHUNK, BATCH), 320, 0, stream>>>(mag, alpha, carry);
  mel_gemm<<<(MROWS + 63) / 64, 256, 0, stream>>>(mag, mel, out);
}

// Round 3
// 340.200 us; speedup vs baseline: 1.8665x; 1.2702x over previous
//
#include <hip/hip_runtime.h>
#include <math.h>

#define NFFT      512
#define HOP       256
#define NBINS     257
#define NMELS     64
#define BATCH     32
#define WAVE_LEN  960000
#define NFRAMES   3751
#define NPAIRS    1876               // ceil(3751/2)
#define CHUNK     128
#define NCHUNK    30                 // ceil(3751/128)
#define MROWS     (BATCH * NFRAMES)  // 120032
#define KPAD      288                // 257 padded up to multiple of 32

#define PI2F 6.283185307179586f

typedef unsigned short ushort_t;
typedef __attribute__((ext_vector_type(8))) short bf16x8;
typedef __attribute__((ext_vector_type(4))) float f32x4;

__device__ __forceinline__ float sigmoidf_(float x) { return 1.0f / (1.0f + __expf(-x)); }

// fp32 -> bf16 round-to-nearest-even
__device__ __forceinline__ ushort_t f2b(float x) {
  unsigned u = __float_as_uint(x);
  u = u + 0x7FFFu + ((u >> 16) & 1u);
  return (ushort_t)(u >> 16);
}
__device__ __forceinline__ float b2f(ushort_t h) {
  return __uint_as_float(((unsigned)h) << 16);
}

// ---------------------------------------------------------------------------
// Kernel 0: window + twiddle tables + mel^T in bf16 (zero-padded K to 288).
// ---------------------------------------------------------------------------
__global__ __launch_bounds__(512) void init_tables(const float* __restrict__ mel,
                                                   float* __restrict__ win,
                                                   float* __restrict__ twA,
                                                   float* __restrict__ twB,
                                                   ushort_t* __restrict__ melbT) {
  const int n = threadIdx.x;
  win[n] = 0.5f - 0.5f * __cosf(PI2F * (float)n / (float)NFFT);
  {
    int j = n >> 6, p = n & 63;
    float ang = -PI2F * (float)(p * j) / 512.0f;
    twA[2 * n]     = __cosf(ang);
    twA[2 * n + 1] = __sinf(ang);
  }
  if (n < 64) {
    int p = n >> 3, j = n & 7;
    float ang = -PI2F * (float)(p * j) / 64.0f;
    twB[2 * n]     = __cosf(ang);
    twB[2 * n + 1] = __sinf(ang);
  }
  // melbT[m][k] = mel[k][m] as bf16, zero for k >= 257
  for (int i = n; i < NMELS * KPAD; i += 512) {
    int m = i / KPAD, k = i - m * KPAD;
    melbT[i] = (k < NBINS) ? f2b(mel[(size_t)k * NMELS + m]) : (ushort_t)0;
  }
}

// 8-point DFT, natural-order in/out.
__device__ __forceinline__ void fft8(float zr[8], float zi[8]) {
  float er[4], ei[4], orr[4], oi[4];
  {
    float Ar = zr[0] + zr[4], Ai = zi[0] + zi[4];
    float Br = zr[2] + zr[6], Bi = zi[2] + zi[6];
    float Cr = zr[0] - zr[4], Ci = zi[0] - zi[4];
    float dr = zr[2] - zr[6], di = zi[2] - zi[6];
    er[0] = Ar + Br; ei[0] = Ai + Bi;
    er[1] = Cr + di; ei[1] = Ci - dr;
    er[2] = Ar - Br; ei[2] = Ai - Bi;
    er[3] = Cr - di; ei[3] = Ci + dr;
  }
  {
    float Ar = zr[1] + zr[5], Ai = zi[1] + zi[5];
    float Br = zr[3] + zr[7], Bi = zi[3] + zi[7];
    float Cr = zr[1] - zr[5], Ci = zi[1] - zi[5];
    float dr = zr[3] - zr[7], di = zi[3] - zi[7];
    orr[0] = Ar + Br; oi[0] = Ai + Bi;
    orr[1] = Cr + di; oi[1] = Ci - dr;
    orr[2] = Ar - Br; oi[2] = Ai - Bi;
    orr[3] = Cr - di; oi[3] = Ci + dr;
  }
  const float R = 0.70710678118654752f;
  zr[0] = er[0] + orr[0]; zi[0] = ei[0] + oi[0];
  zr[4] = er[0] - orr[0]; zi[4] = ei[0] - oi[0];
  {
    float tr = R * (orr[1] + oi[1]);
    float ti = R * (oi[1] - orr[1]);
    zr[1] = er[1] + tr; zi[1] = ei[1] + ti;
    zr[5] = er[1] - tr; zi[5] = ei[1] - ti;
  }
  {
    float tr = oi[2], ti = -orr[2];
    zr[2] = er[2] + tr; zi[2] = ei[2] + ti;
    zr[6] = er[2] - tr; zi[6] = ei[2] - ti;
  }
  {
    float tr = R * (oi[3] - orr[3]);
    float ti = -R * (orr[3] + oi[3]);
    zr[3] = er[3] + tr; zi[3] = ei[3] + ti;
    zr[7] = er[3] - tr; zi[7] = ei[3] - ti;
  }
}

// ---------------------------------------------------------------------------
// Kernel 1: STFT magnitude (bf16 out). One wave per frame-pair, radix-8 FFT.
// ---------------------------------------------------------------------------
__global__ __launch_bounds__(64) void stft_kernel(const float* __restrict__ wav,
                                                  const float* __restrict__ win,
                                                  const float* __restrict__ twA,
                                                  const float* __restrict__ twB,
                                                  ushort_t* __restrict__ mag) {
  const int pr  = blockIdx.x;
  const int b   = blockIdx.y;
  const int tid = threadIdx.x;

  __shared__ float sre[576], sim[576];

  const float* w = wav + (size_t)b * WAVE_LEN;
  const int f0 = 2 * pr, f1 = f0 + 1;
  const bool has1 = (f1 < NFRAMES);
  const int base0 = f0 * HOP - (NFFT / 2);
  const int base1 = base0 + HOP;

  float zr[8], zi[8];
#pragma unroll
  for (int j = 0; j < 8; ++j) {
    int n = tid + 64 * j;
    float wn = win[n];
    int p0 = base0 + n;
    p0 = (p0 < 0) ? -p0 : p0;
    p0 = (p0 >= WAVE_LEN) ? (2 * WAVE_LEN - 2 - p0) : p0;
    float x0 = w[p0];
    float x1 = has1 ? w[base1 + n] : 0.0f;
    zr[j] = x0 * wn;
    zi[j] = x1 * wn;
  }

  // stage A: span 64
  fft8(zr, zi);
  const float2* twA2 = (const float2*)twA;
#pragma unroll
  for (int j = 1; j < 8; ++j) {
    float2 t = twA2[j * 64 + tid];
    float r = zr[j] * t.x - zi[j] * t.y;
    zi[j]   = zi[j] * t.x + zr[j] * t.y;
    zr[j]   = r;
  }

#pragma unroll
  for (int j = 0; j < 8; ++j) {
    int n = tid + 64 * j;
    int a = n + (n >> 3);
    sre[a] = zr[j]; sim[a] = zi[j];
  }
  __syncthreads();
  const int g = tid >> 3, q = tid & 7;
#pragma unroll
  for (int j = 0; j < 8; ++j) {
    int n = g * 64 + q + 8 * j;
    int a = n + (n >> 3);
    zr[j] = sre[a]; zi[j] = sim[a];
  }

  // stage B: span 8
  fft8(zr, zi);
  const float2* twB2 = (const float2*)twB;
#pragma unroll
  for (int j = 1; j < 8; ++j) {
    float2 t = twB2[q * 8 + j];
    float r = zr[j] * t.x - zi[j] * t.y;
    zi[j]   = zi[j] * t.x + zr[j] * t.y;
    zr[j]   = r;
  }

  __syncthreads();
#pragma unroll
  for (int j = 0; j < 8; ++j) {
    int n = g * 64 + q + 8 * j;
    int a = n + (n >> 3);
    sre[a] = zr[j]; sim[a] = zi[j];
  }
  __syncthreads();
#pragma unroll
  for (int j = 0; j < 8; ++j) {
    int n = 8 * tid + j;
    int a = n + (n >> 3);
    zr[j] = sre[a]; zi[j] = sim[a];
  }

  // stage C
  fft8(zr, zi);

  __syncthreads();
#pragma unroll
  for (int j = 0; j < 8; ++j) {
    int k = 64 * j + 8 * q + g;
    sre[k] = zr[j]; sim[k] = zi[j];
  }
  __syncthreads();

  ushort_t* out0 = mag + ((size_t)b * NFRAMES + f0) * NBINS;
  ushort_t* out1 = out0 + NBINS;
  for (int k = tid; k <= 256; k += 64) {
    int kn = (NFFT - k) & (NFFT - 1);
    float ar = sre[k],  ai = sim[k];
    float br = sre[kn], bi = sim[kn];
    float xr = ar + br, xi = ai - bi;
    float yr = ai + bi, yi = ar - br;
    out0[k] = f2b(0.5f * sqrtf(xr * xr + xi * xi));
    if (has1) out1[k] = f2b(0.5f * sqrtf(yr * yr + yi * yi));
  }
}

// ---------------------------------------------------------------------------
// Kernel 2: per-chunk partial (zero-carry) EMA sums.
// ---------------------------------------------------------------------------
__global__ void scan_partial(const ushort_t* __restrict__ mag,
                             const float* __restrict__ alpha,
                             float* __restrict__ Bc) {
  const int c = blockIdx.x, b = blockIdx.y, f = threadIdx.x;
  if (f >= NBINS) return;
  const float a = sigmoidf_(alpha[f]);
  const float om = 1.0f - a;
  const int t0 = c * CHUNK;
  const int t1 = min(NFRAMES, t0 + CHUNK);
  const ushort_t* p = mag + ((size_t)b * NFRAMES + t0) * NBINS + f;
  float v = 0.0f;
  for (int t = t0; t < t1; ++t) {
    v = fmaf(a, v, om * b2f(*p));
    p += NBINS;
  }
  Bc[((size_t)b * NBINS + f) * NCHUNK + c] = v;
}

// ---------------------------------------------------------------------------
// Kernel 3: propagate carries across chunks.
// ---------------------------------------------------------------------------
__global__ void scan_combine(const ushort_t* __restrict__ mag,
                             const float* __restrict__ alpha,
                             const float* __restrict__ Bc,
                             float* __restrict__ carry) {
  const int b = blockIdx.x, f = threadIdx.x;
  if (f >= NBINS) return;
  const float a = sigmoidf_(alpha[f]);
  float aL = a;  // a^128 via 7 squarings
#pragma unroll
  for (int i = 0; i < 7; ++i) aL *= aL;
  float v = b2f(mag[(size_t)b * NFRAMES * NBINS + f]);
  const size_t off = ((size_t)b * NBINS + f) * NCHUNK;
  for (int c = 0; c < NCHUNK; ++c) {
    carry[off + c] = v;
    v = fmaf(aL, v, Bc[off + c]);
  }
}

// ---------------------------------------------------------------------------
// Kernel 4: local scan with true carry -> norm (bf16) into K-padded buffer.
// Threads 257..287 zero the pad columns.
// ---------------------------------------------------------------------------
__global__ void scan_apply(const ushort_t* __restrict__ mag,
                           const float* __restrict__ alpha,
                           const float* __restrict__ carry,
                           ushort_t* __restrict__ normb) {
  const int c = blockIdx.x, b = blockIdx.y, f = threadIdx.x;
  if (f >= KPAD) return;
  const int t0 = c * CHUNK;
  const int t1 = min(NFRAMES, t0 + CHUNK);
  if (f >= NBINS) {  // zero pad columns
    ushort_t* q = normb + ((size_t)b * NFRAMES + t0) * KPAD + f;
    for (int t = t0; t < t1; ++t) { *q = 0; q += KPAD; }
    return;
  }
  const float a = sigmoidf_(alpha[f]);
  const float om = 1.0f - a;
  float v = carry[((size_t)b * NBINS + f) * NCHUNK + c];
  const ushort_t* p = mag + ((size_t)b * NFRAMES + t0) * NBINS + f;
  ushort_t* q = normb + ((size_t)b * NFRAMES + t0) * KPAD + f;
  for (int t = t0; t < t1; ++t) {
    float m = b2f(*p);
    v = fmaf(a, v, om * m);
    *q = f2b(m / (v + 1e-8f));
    p += NBINS;
    q += KPAD;
  }
}

// ---------------------------------------------------------------------------
// Kernel 5: mel GEMM via MFMA 16x16x32 bf16. A (normb) straight from global,
// B (melbT, 36.9 KB) from global (L1/L2-hot). Each wave: 16 rows x 64 cols.
// ---------------------------------------------------------------------------
__global__ __launch_bounds__(256) void mel_gemm_mfma(const ushort_t* __restrict__ normb,
                                                     const ushort_t* __restrict__ melbT,
                                                     float* __restrict__ out) {
  const int wave = threadIdx.x >> 6;
  const int lane = threadIdx.x & 63;
  const int rt = blockIdx.x * 4 + wave;           // 16-row tile index
  if (rt * 16 >= MROWS) return;
  const int row0 = rt * 16;
  const int m    = lane & 15;                     // A row / B col / C col
  const int quad = lane >> 4;                     // k-offset group

  const ushort_t* Ap = normb + (size_t)(row0 + m) * KPAD + quad * 8;

  f32x4 acc[4];
#pragma unroll
  for (int ct = 0; ct < 4; ++ct) acc[ct] = (f32x4){0.f, 0.f, 0.f, 0.f};

#pragma unroll
  for (int ks = 0; ks < 9; ++ks) {
    bf16x8 a = *(const bf16x8*)(Ap + ks * 32);
#pragma unroll
    for (int ct = 0; ct < 4; ++ct) {
      bf16x8 bb = *(const bf16x8*)(melbT + (size_t)(ct * 16 + m) * KPAD + ks * 32 + quad * 8);
      acc[ct] = __builtin_amdgcn_mfma_f32_16x16x32_bf16(a, bb, acc[ct], 0, 0, 0);
    }
  }

  // C/D layout: col = lane&15, row = quad*4 + r
#pragma unroll
  for (int ct = 0; ct < 4; ++ct) {
#pragma unroll
    for (int r = 0; r < 4; ++r) {
      int row = row0 + quad * 4 + r;
      out[(size_t)row * NMELS + ct * 16 + m] = acc[ct][r] + 1e-6f;
    }
  }
}

// ---------------------------------------------------------------------------
extern "C" void kernel_launch(void* const* d_in, const int* in_sizes, int n_in,
                              void* d_out, int out_size, void* d_ws, size_t ws_size,
                              hipStream_t stream) {
  const float* wav   = (const float*)d_in[0];
  const float* alpha = (const float*)d_in[1];
  const float* mel   = (const float*)d_in[2];
  float* out = (float*)d_out;

  // workspace layout (bytes): all blocks 64B-aligned by construction
  ushort_t* magb  = (ushort_t*)d_ws;                          // 32*3751*257 bf16
  ushort_t* normb = magb + (size_t)BATCH * NFRAMES * NBINS;   // 120032*288 bf16
  ushort_t* melbT = normb + (size_t)MROWS * KPAD;             // 64*288 bf16
  float* Bc    = (float*)(melbT + (size_t)NMELS * KPAD);      // 32*257*30
  float* carry = Bc + (size_t)BATCH * NBINS * NCHUNK;         // 32*257*30
  float* win   = carry + (size_t)BATCH * NBINS * NCHUNK;      // 512
  float* twA   = win + 512;                                   // 1024
  float* twB   = twA + 1024;                                  // 128

  init_tables<<<1, 512, 0, stream>>>(mel, win, twA, twB, melbT);
  stft_kernel<<<dim3(NPAIRS, BATCH), 64, 0, stream>>>(wav, win, twA, twB, magb);
  scan_partial<<<dim3(NCHUNK, BATCH), 320, 0, stream>>>(magb, alpha, Bc);
  scan_combine<<<BATCH, 320, 0, stream>>>(magb, alpha, Bc, carry);
  scan_apply<<<dim3(NCHUNK, BATCH), 320, 0, stream>>>(magb, alpha, carry, normb);
  mel_gemm_mfma<<<(MROWS + 63) / 64, 256, 0, stream>>>(normb, melbT, out);
}

// Round 4
// 315.490 us; speedup vs baseline: 2.0127x; 1.0783x over previous
//
#include <hip/hip_runtime.h>
#include <math.h>

#define NFFT      512
#define HOP       256
#define NBINS     257
#define NMELS     64
#define BATCH     32
#define WAVE_LEN  960000
#define NFRAMES   3751
#define NPAIRS    1876               // ceil(3751/2)
#define CHUNK     64
#define NCHUNK    59                 // ceil(3751/64)
#define MROWS     (BATCH * NFRAMES)  // 120032
#define KPAD      288                // 257 padded up to multiple of 32
#define LDSW      296                // LDS row stride (bf16): 592B, 16B-aligned, 2-way banks

#define PI2F 6.283185307179586f

typedef unsigned short ushort_t;
typedef __attribute__((ext_vector_type(2))) float f32x2;
typedef __attribute__((ext_vector_type(8))) short bf16x8;
typedef __attribute__((ext_vector_type(4))) float f32x4;

__device__ __forceinline__ float sigmoidf_(float x) { return 1.0f / (1.0f + __expf(-x)); }

// fp32 -> bf16 round-to-nearest-even
__device__ __forceinline__ ushort_t f2b(float x) {
  unsigned u = __float_as_uint(x);
  u = u + 0x7FFFu + ((u >> 16) & 1u);
  return (ushort_t)(u >> 16);
}
__device__ __forceinline__ float b2f(ushort_t h) {
  return __uint_as_float(((unsigned)h) << 16);
}

// ---------------------------------------------------------------------------
// Kernel 0: window + twiddle tables + mel^T in bf16 (zero-padded K to 288).
// ---------------------------------------------------------------------------
__global__ __launch_bounds__(512) void init_tables(const float* __restrict__ mel,
                                                   float* __restrict__ win,
                                                   float* __restrict__ twA,
                                                   float* __restrict__ twB,
                                                   ushort_t* __restrict__ melbT) {
  const int n = threadIdx.x;
  win[n] = 0.5f - 0.5f * __cosf(PI2F * (float)n / (float)NFFT);
  {
    int j = n >> 6, p = n & 63;
    float ang = -PI2F * (float)(p * j) / 512.0f;
    twA[2 * n]     = __cosf(ang);
    twA[2 * n + 1] = __sinf(ang);
  }
  if (n < 64) {
    int p = n >> 3, j = n & 7;
    float ang = -PI2F * (float)(p * j) / 64.0f;
    twB[2 * n]     = __cosf(ang);
    twB[2 * n + 1] = __sinf(ang);
  }
  // melbT[m][k] = mel[k][m] as bf16, zero for k >= 257
  for (int i = n; i < NMELS * KPAD; i += 512) {
    int m = i / KPAD, k = i - m * KPAD;
    melbT[i] = (k < NBINS) ? f2b(mel[(size_t)k * NMELS + m]) : (ushort_t)0;
  }
}

// complex * (c + i s)
__device__ __forceinline__ f32x2 cmulw(f32x2 a, float c, float s) {
  return (f32x2){a.x * c - a.y * s, a.y * c + a.x * s};
}

// 8-point DFT on packed (re,im) f32x2 — add/sub ops map to v_pk_*_f32.
__device__ __forceinline__ void fft8v(f32x2 z[8]) {
  f32x2 e[4], o[4];
  {
    f32x2 A = z[0] + z[4], C = z[0] - z[4];
    f32x2 B = z[2] + z[6], D = z[2] - z[6];
    f32x2 Dn = (f32x2){D.y, -D.x};          // -i * D
    e[0] = A + B; e[2] = A - B; e[1] = C + Dn; e[3] = C - Dn;
  }
  {
    f32x2 A = z[1] + z[5], C = z[1] - z[5];
    f32x2 B = z[3] + z[7], D = z[3] - z[7];
    f32x2 Dn = (f32x2){D.y, -D.x};
    o[0] = A + B; o[2] = A - B; o[1] = C + Dn; o[3] = C - Dn;
  }
  const float R = 0.70710678118654752f;
  z[0] = e[0] + o[0]; z[4] = e[0] - o[0];
  f32x2 t1 = (f32x2){R * (o[1].x + o[1].y), R * (o[1].y - o[1].x)};  // o1 * W8
  z[1] = e[1] + t1; z[5] = e[1] - t1;
  f32x2 t2 = (f32x2){o[2].y, -o[2].x};                               // o2 * -i
  z[2] = e[2] + t2; z[6] = e[2] - t2;
  f32x2 t3 = (f32x2){R * (o[3].y - o[3].x), -R * (o[3].x + o[3].y)}; // o3 * W8^3
  z[3] = e[3] + t3; z[7] = e[3] - t3;
}

// ---------------------------------------------------------------------------
// Kernel 1: STFT magnitude (bf16 out). One wave per frame-pair, radix-8 FFT,
// packed-f32 complex math, f32x2 LDS exchanges (tau(n)=n+(n>>3) padding).
// ---------------------------------------------------------------------------
__global__ __launch_bounds__(64) void stft_kernel(const float* __restrict__ wav,
                                                  const float* __restrict__ win,
                                                  const float* __restrict__ twA,
                                                  const float* __restrict__ twB,
                                                  ushort_t* __restrict__ mag) {
  const int pr  = blockIdx.x;
  const int b   = blockIdx.y;
  const int tid = threadIdx.x;

  __shared__ f32x2 sz[576];

  const float* w = wav + (size_t)b * WAVE_LEN;
  const int f0 = 2 * pr, f1 = f0 + 1;
  const bool has1 = (f1 < NFRAMES);
  const int base0 = f0 * HOP - (NFFT / 2);
  const int base1 = base0 + HOP;

  f32x2 z[8];
#pragma unroll
  for (int j = 0; j < 8; ++j) {
    int n = tid + 64 * j;
    float wn = win[n];
    int p0 = base0 + n;
    p0 = (p0 < 0) ? -p0 : p0;
    p0 = (p0 >= WAVE_LEN) ? (2 * WAVE_LEN - 2 - p0) : p0;
    float x0 = w[p0];
    float x1 = has1 ? w[base1 + n] : 0.0f;
    z[j] = (f32x2){x0 * wn, x1 * wn};
  }

  // stage A: span 64, twiddle W_512^{tid*j}
  fft8v(z);
  const float2* twA2 = (const float2*)twA;
#pragma unroll
  for (int j = 1; j < 8; ++j) {
    float2 t = twA2[j * 64 + tid];
    z[j] = cmulw(z[j], t.x, t.y);
  }

#pragma unroll
  for (int j = 0; j < 8; ++j) {
    int n = tid + 64 * j;
    sz[n + (n >> 3)] = z[j];
  }
  __syncthreads();
  const int g = tid >> 3, q = tid & 7;
#pragma unroll
  for (int j = 0; j < 8; ++j) {
    int n = g * 64 + q + 8 * j;
    z[j] = sz[n + (n >> 3)];
  }

  // stage B: span 8, twiddle W_64^{q*j}
  fft8v(z);
  const float2* twB2 = (const float2*)twB;
#pragma unroll
  for (int j = 1; j < 8; ++j) {
    float2 t = twB2[q * 8 + j];
    z[j] = cmulw(z[j], t.x, t.y);
  }

  __syncthreads();
#pragma unroll
  for (int j = 0; j < 8; ++j) {
    int n = g * 64 + q + 8 * j;
    sz[n + (n >> 3)] = z[j];
  }
  __syncthreads();
#pragma unroll
  for (int j = 0; j < 8; ++j) {
    z[j] = sz[9 * tid + j];  // tau(8*tid+j)
  }

  // stage C: span 1
  fft8v(z);

  __syncthreads();
#pragma unroll
  for (int j = 0; j < 8; ++j) {
    int k = 64 * j + 8 * q + g;   // natural bin order
    sz[k] = z[j];
  }
  __syncthreads();

  ushort_t* out0 = mag + ((size_t)b * NFRAMES + f0) * NBINS;
  ushort_t* out1 = out0 + NBINS;
  for (int k = tid; k <= 256; k += 64) {
    int kn = (NFFT - k) & (NFFT - 1);
    f32x2 A = sz[k], B = sz[kn];
    float xr = A.x + B.x, xi = A.y - B.y;   // 2*X_frame0
    float yr = A.y + B.y, yi = A.x - B.x;   // 2*X_frame1
    out0[k] = f2b(0.5f * sqrtf(xr * xr + xi * xi));
    if (has1) out1[k] = f2b(0.5f * sqrtf(yr * yr + yi * yi));
  }
}

// ---------------------------------------------------------------------------
// Kernel 2: per-chunk partial (zero-carry) EMA sums.
// ---------------------------------------------------------------------------
__global__ void scan_partial(const ushort_t* __restrict__ mag,
                             const float* __restrict__ alpha,
                             float* __restrict__ Bc) {
  const int c = blockIdx.x, b = blockIdx.y, f = threadIdx.x;
  if (f >= NBINS) return;
  const float a = sigmoidf_(alpha[f]);
  const float om = 1.0f - a;
  const int t0 = c * CHUNK;
  const int t1 = min(NFRAMES, t0 + CHUNK);
  const ushort_t* p = mag + ((size_t)b * NFRAMES + t0) * NBINS + f;
  float v = 0.0f;
  for (int t = t0; t < t1; ++t) {
    v = fmaf(a, v, om * b2f(*p));
    p += NBINS;
  }
  Bc[((size_t)b * NBINS + f) * NCHUNK + c] = v;
}

// ---------------------------------------------------------------------------
// Kernel 3: propagate carries across chunks.
// ---------------------------------------------------------------------------
__global__ void scan_combine(const ushort_t* __restrict__ mag,
                             const float* __restrict__ alpha,
                             const float* __restrict__ Bc,
                             float* __restrict__ carry) {
  const int b = blockIdx.x, f = threadIdx.x;
  if (f >= NBINS) return;
  const float a = sigmoidf_(alpha[f]);
  float aL = a;  // a^64 via 6 squarings
#pragma unroll
  for (int i = 0; i < 6; ++i) aL *= aL;
  float v = b2f(mag[(size_t)b * NFRAMES * NBINS + f]);
  const size_t off = ((size_t)b * NBINS + f) * NCHUNK;
  for (int c = 0; c < NCHUNK; ++c) {
    carry[off + c] = v;
    v = fmaf(aL, v, Bc[off + c]);
  }
}

// ---------------------------------------------------------------------------
// Kernel 4 (fused): EMA-normalize one (b, chunk) tile into LDS (bf16), then
// MFMA GEMM vs melbT straight to out. Kills the normb HBM round-trip.
// ---------------------------------------------------------------------------
__global__ __launch_bounds__(256) void scan_gemm(const ushort_t* __restrict__ magb,
                                                 const float* __restrict__ alpha,
                                                 const float* __restrict__ carry,
                                                 const ushort_t* __restrict__ melbT,
                                                 float* __restrict__ out) {
  const int c = blockIdx.x, b = blockIdx.y;
  const int tid = threadIdx.x;
  const int t0 = c * CHUNK;
  const int nv = min(CHUNK, NFRAMES - t0);

  __shared__ __align__(16) ushort_t Ns[CHUNK][LDSW];

  // phase 1: EMA + normalize into LDS
  for (int f = tid; f < KPAD; f += 256) {
    if (f < NBINS) {
      const float a = sigmoidf_(alpha[f]);
      const float om = 1.0f - a;
      float v = carry[((size_t)b * NBINS + f) * NCHUNK + c];
      const ushort_t* p = magb + ((size_t)b * NFRAMES + t0) * NBINS + f;
      int t = 0;
      for (; t < nv; ++t) {
        float m = b2f(*p);
        v = fmaf(a, v, om * m);
        Ns[t][f] = f2b(m / (v + 1e-8f));
        p += NBINS;
      }
      for (; t < CHUNK; ++t) Ns[t][f] = 0;
    } else {
      for (int t = 0; t < CHUNK; ++t) Ns[t][f] = 0;
    }
  }
  __syncthreads();

  // phase 2: (64 x 288) @ (288 x 64) via MFMA 16x16x32 bf16
  const int wave = tid >> 6, lane = tid & 63;
  const int m = lane & 15, quad = lane >> 4;
  const int r0 = wave * 16;

  f32x4 acc[4];
#pragma unroll
  for (int ct = 0; ct < 4; ++ct) acc[ct] = (f32x4){0.f, 0.f, 0.f, 0.f};

#pragma unroll
  for (int ks = 0; ks < 9; ++ks) {
    bf16x8 a = *(const bf16x8*)&Ns[r0 + m][ks * 32 + quad * 8];
#pragma unroll
    for (int ct = 0; ct < 4; ++ct) {
      bf16x8 bb = *(const bf16x8*)(melbT + (size_t)(ct * 16 + m) * KPAD + ks * 32 + quad * 8);
      acc[ct] = __builtin_amdgcn_mfma_f32_16x16x32_bf16(a, bb, acc[ct], 0, 0, 0);
    }
  }

#pragma unroll
  for (int ct = 0; ct < 4; ++ct) {
#pragma unroll
    for (int r = 0; r < 4; ++r) {
      int tl = r0 + quad * 4 + r;
      if (t0 + tl < NFRAMES)
        out[((size_t)b * NFRAMES + t0 + tl) * NMELS + ct * 16 + m] = acc[ct][r] + 1e-6f;
    }
  }
}

// ---------------------------------------------------------------------------
extern "C" void kernel_launch(void* const* d_in, const int* in_sizes, int n_in,
                              void* d_out, int out_size, void* d_ws, size_t ws_size,
                              hipStream_t stream) {
  const float* wav   = (const float*)d_in[0];
  const float* alpha = (const float*)d_in[1];
  const float* mel   = (const float*)d_in[2];
  float* out = (float*)d_out;

  // workspace layout
  ushort_t* magb  = (ushort_t*)d_ws;                          // 32*3751*257 bf16
  ushort_t* melbT = magb + (size_t)BATCH * NFRAMES * NBINS;   // 64*288 bf16
  float* Bc    = (float*)(melbT + (size_t)NMELS * KPAD);      // 32*257*59
  float* carry = Bc + (size_t)BATCH * NBINS * NCHUNK;         // 32*257*59
  float* win   = carry + (size_t)BATCH * NBINS * NCHUNK;      // 512
  float* twA   = win + 512;                                   // 1024
  float* twB   = twA + 1024;                                  // 128

  init_tables<<<1, 512, 0, stream>>>(mel, win, twA, twB, melbT);
  stft_kernel<<<dim3(NPAIRS, BATCH), 64, 0, stream>>>(wav, win, twA, twB, magb);
  scan_partial<<<dim3(NCHUNK, BATCH), 320, 0, stream>>>(magb, alpha, Bc);
  scan_combine<<<BATCH, 320, 0, stream>>>(magb, alpha, Bc, carry);
  scan_gemm<<<dim3(NCHUNK, BATCH), 256, 0, stream>>>(magb, alpha, carry, melbT, out);
}

// Round 6
// 306.767 us; speedup vs baseline: 2.0699x; 1.0284x over previous
//
#include <hip/hip_runtime.h>
#include <math.h>

#define NFFT      512
#define HOP       256
#define NBINS     257
#define NMELS     64
#define BATCH     32
#define WAVE_LEN  960000
#define NFRAMES   3751
#define NPAIRS    1876               // = 4 * 469 exactly
#define CH1       8                  // frames per stft_scan block (fine chunk)
#define NCH1      469                // 3752/8 (last chunk has 7 real frames)
#define CHG       64                 // frames per scan_gemm block
#define NCHG      59                 // ceil(3751/64)
#define MROWS     (BATCH * NFRAMES)  // 120032
#define KPAD      288                // 257 padded to multiple of 32
#define LDSW      296                // scan_gemm LDS row stride (bf16)

#define PI2F 6.283185307179586f

typedef unsigned short ushort_t;
typedef __attribute__((ext_vector_type(2))) float f32x2;
typedef __attribute__((ext_vector_type(8))) short bf16x8;
typedef __attribute__((ext_vector_type(4))) float f32x4;

__device__ __forceinline__ float sigmoidf_(float x) { return 1.0f / (1.0f + __expf(-x)); }

// fp32 -> bf16 round-to-nearest-even
__device__ __forceinline__ ushort_t f2b(float x) {
  unsigned u = __float_as_uint(x);
  u = u + 0x7FFFu + ((u >> 16) & 1u);
  return (ushort_t)(u >> 16);
}
__device__ __forceinline__ float b2f(ushort_t h) {
  return __uint_as_float(((unsigned)h) << 16);
}

// ---------------------------------------------------------------------------
// Kernel 0: window + twiddle tables + mel^T in bf16 (zero-padded K to 288).
// ---------------------------------------------------------------------------
__global__ __launch_bounds__(512) void init_tables(const float* __restrict__ mel,
                                                   float* __restrict__ win,
                                                   float* __restrict__ twA,
                                                   float* __restrict__ twB,
                                                   ushort_t* __restrict__ melbT) {
  const int n = threadIdx.x;
  win[n] = 0.5f - 0.5f * __cosf(PI2F * (float)n / (float)NFFT);
  {
    int j = n >> 6, p = n & 63;
    float ang = -PI2F * (float)(p * j) / 512.0f;
    twA[2 * n]     = __cosf(ang);
    twA[2 * n + 1] = __sinf(ang);
  }
  if (n < 64) {
    int p = n >> 3, j = n & 7;
    float ang = -PI2F * (float)(p * j) / 64.0f;
    twB[2 * n]     = __cosf(ang);
    twB[2 * n + 1] = __sinf(ang);
  }
  for (int i = n; i < NMELS * KPAD; i += 512) {
    int m = i / KPAD, k = i - m * KPAD;
    melbT[i] = (k < NBINS) ? f2b(mel[(size_t)k * NMELS + m]) : (ushort_t)0;
  }
}

__device__ __forceinline__ f32x2 cmulw(f32x2 a, float c, float s) {
  return (f32x2){a.x * c - a.y * s, a.y * c + a.x * s};
}

// 8-point DFT on packed (re,im) f32x2.
__device__ __forceinline__ void fft8v(f32x2 z[8]) {
  f32x2 e[4], o[4];
  {
    f32x2 A = z[0] + z[4], C = z[0] - z[4];
    f32x2 B = z[2] + z[6], D = z[2] - z[6];
    f32x2 Dn = (f32x2){D.y, -D.x};
    e[0] = A + B; e[2] = A - B; e[1] = C + Dn; e[3] = C - Dn;
  }
  {
    f32x2 A = z[1] + z[5], C = z[1] - z[5];
    f32x2 B = z[3] + z[7], D = z[3] - z[7];
    f32x2 Dn = (f32x2){D.y, -D.x};
    o[0] = A + B; o[2] = A - B; o[1] = C + Dn; o[3] = C - Dn;
  }
  const float R = 0.70710678118654752f;
  z[0] = e[0] + o[0]; z[4] = e[0] - o[0];
  f32x2 t1 = (f32x2){R * (o[1].x + o[1].y), R * (o[1].y - o[1].x)};
  z[1] = e[1] + t1; z[5] = e[1] - t1;
  f32x2 t2 = (f32x2){o[2].y, -o[2].x};
  z[2] = e[2] + t2; z[6] = e[2] - t2;
  f32x2 t3 = (f32x2){R * (o[3].y - o[3].x), -R * (o[3].x + o[3].y)};
  z[3] = e[3] + t3; z[7] = e[3] - t3;
}

// ---------------------------------------------------------------------------
// Kernel 1 (fused): STFT + fine-chunk EMA partials. One wave per 8-frame
// chunk (4 frame-pairs). Twiddles/window hoisted; EMA partials in registers
// (using bf16-rounded magnitudes for bit-consistency with scan_gemm).
// Reflect: BOTH edges handled in slow path; fast path requires full in-range.
// ---------------------------------------------------------------------------
__global__ __launch_bounds__(64) void stft_scan(const float* __restrict__ wav,
                                                const float* __restrict__ win,
                                                const float* __restrict__ twA,
                                                const float* __restrict__ twB,
                                                const float* __restrict__ alpha,
                                                ushort_t* __restrict__ mag,
                                                float* __restrict__ Bc) {
  const int u   = blockIdx.x;   // fine chunk: frames 8u .. 8u+7
  const int b   = blockIdx.y;
  const int tid = threadIdx.x;
  const int g = tid >> 3, q = tid & 7;

  __shared__ float sre[576], sim[576];

  // hoisted per-wave constants
  const float2* twA2 = (const float2*)twA;
  const float2* twB2 = (const float2*)twB;
  float2 tA[7], tB[7];
#pragma unroll
  for (int j = 1; j < 8; ++j) tA[j - 1] = twA2[j * 64 + tid];
#pragma unroll
  for (int j = 1; j < 8; ++j) tB[j - 1] = twB2[q * 8 + j];
  float wv[8];
#pragma unroll
  for (int j = 0; j < 8; ++j) wv[j] = win[tid + 64 * j];

  // EMA coefficients for this lane's 5 bins (f = tid+64i, and bin 256)
  float av[5], omv[5];
#pragma unroll
  for (int i = 0; i < 4; ++i) {
    float a = sigmoidf_(alpha[tid + 64 * i]);
    av[i] = a; omv[i] = 1.0f - a;
  }
  {
    float a = sigmoidf_(alpha[256]);
    av[4] = a; omv[4] = 1.0f - a;
  }
  float v[5] = {0.f, 0.f, 0.f, 0.f, 0.f};

  const float* w = wav + (size_t)b * WAVE_LEN;

  for (int pi = 0; pi < 4; ++pi) {
    const int pr = 4 * u + pi;
    const int f0 = 2 * pr, f1 = f0 + 1;
    const bool has1 = (f1 < NFRAMES);
    const int base0 = f0 * HOP - (NFFT / 2);
    const int base1 = base0 + HOP;  // f1>=1 -> base1>=0; base1+511 <= WAVE_LEN-1 always

    f32x2 z[8];
    if (base0 >= 0 && base0 + NFFT <= WAVE_LEN) {  // fully in range
#pragma unroll
      for (int j = 0; j < 8; ++j) {
        int n = tid + 64 * j;
        float x0 = w[base0 + n];
        float x1 = has1 ? w[base1 + n] : 0.0f;
        z[j] = (f32x2){x0 * wv[j], x1 * wv[j]};
      }
    } else {  // reflect both edges (first pair, last pair)
#pragma unroll
      for (int j = 0; j < 8; ++j) {
        int n = tid + 64 * j;
        int p0 = base0 + n;
        p0 = (p0 < 0) ? -p0 : p0;
        p0 = (p0 >= WAVE_LEN) ? (2 * WAVE_LEN - 2 - p0) : p0;
        float x0 = w[p0];
        float x1 = has1 ? w[base1 + n] : 0.0f;
        z[j] = (f32x2){x0 * wv[j], x1 * wv[j]};
      }
    }

    // stage A: span 64
    fft8v(z);
#pragma unroll
    for (int j = 1; j < 8; ++j) z[j] = cmulw(z[j], tA[j - 1].x, tA[j - 1].y);

#pragma unroll
    for (int j = 0; j < 8; ++j) {
      int n = tid + 64 * j;
      int a = n + (n >> 3);
      sre[a] = z[j].x; sim[a] = z[j].y;
    }
    __syncthreads();
#pragma unroll
    for (int j = 0; j < 8; ++j) {
      int n = g * 64 + q + 8 * j;
      int a = n + (n >> 3);
      z[j] = (f32x2){sre[a], sim[a]};
    }

    // stage B: span 8
    fft8v(z);
#pragma unroll
    for (int j = 1; j < 8; ++j) z[j] = cmulw(z[j], tB[j - 1].x, tB[j - 1].y);

    __syncthreads();
#pragma unroll
    for (int j = 0; j < 8; ++j) {
      int n = g * 64 + q + 8 * j;
      int a = n + (n >> 3);
      sre[a] = z[j].x; sim[a] = z[j].y;
    }
    __syncthreads();
#pragma unroll
    for (int j = 0; j < 8; ++j) {
      int a = 9 * tid + j;  // tau(8*tid+j)
      z[j] = (f32x2){sre[a], sim[a]};
    }

    // stage C: span 1
    fft8v(z);

    __syncthreads();
#pragma unroll
    for (int j = 0; j < 8; ++j) {
      int k = 64 * j + 8 * q + g;   // natural bin order
      sre[k] = z[j].x; sim[k] = z[j].y;
    }
    __syncthreads();

    // magnitudes + EMA updates (on bf16-rounded values for consistency)
    ushort_t* out0 = mag + ((size_t)b * NFRAMES + f0) * NBINS;
    ushort_t* out1 = out0 + NBINS;
#pragma unroll
    for (int i = 0; i < 4; ++i) {
      int k = tid + 64 * i;
      int kn = (NFFT - k) & (NFFT - 1);
      float ar = sre[k],  ai = sim[k];
      float br = sre[kn], bi = sim[kn];
      float xr = ar + br, xi = ai - bi;
      float yr = ai + bi, yi = ar - br;
      ushort_t h0 = f2b(0.5f * __builtin_amdgcn_sqrtf(xr * xr + xi * xi));
      ushort_t h1 = f2b(0.5f * __builtin_amdgcn_sqrtf(yr * yr + yi * yi));
      out0[k] = h0;
      v[i] = fmaf(av[i], v[i], omv[i] * b2f(h0));
      if (has1) {
        out1[k] = h1;
        v[i] = fmaf(av[i], v[i], omv[i] * b2f(h1));
      }
    }
    {  // bin 256 (uniform math; lane 0 stores)
      ushort_t h0 = f2b(fabsf(sre[256]));
      ushort_t h1 = f2b(fabsf(sim[256]));
      if (tid == 0) out0[256] = h0;
      v[4] = fmaf(av[4], v[4], omv[4] * b2f(h0));
      if (has1) {
        if (tid == 0) out1[256] = h1;
        v[4] = fmaf(av[4], v[4], omv[4] * b2f(h1));
      }
    }
    __syncthreads();
  }

  // write fine-chunk partials: layout Bc[(b*NCH1 + u)*NBINS + f] (coalesced)
  float* bco = Bc + ((size_t)b * NCH1 + u) * NBINS;
#pragma unroll
  for (int i = 0; i < 4; ++i) bco[tid + 64 * i] = v[i];
  if (tid == 0) bco[256] = v[4];
}

// ---------------------------------------------------------------------------
// Kernel 2: propagate carries across 469 fine chunks. carry[u] = EMA state
// entering chunk u. init = mag[b,0,f] (reference scan init).
// ---------------------------------------------------------------------------
__global__ void scan_combine(const ushort_t* __restrict__ mag,
                             const float* __restrict__ alpha,
                             const float* __restrict__ Bc,
                             float* __restrict__ carry) {
  const int b = blockIdx.x, f = threadIdx.x;
  if (f >= NBINS) return;
  const float a = sigmoidf_(alpha[f]);
  float aL = a;  // a^8 via 3 squarings
#pragma unroll
  for (int i = 0; i < 3; ++i) aL *= aL;
  float v = b2f(mag[(size_t)b * NFRAMES * NBINS + f]);
  const float* bcp = Bc + (size_t)b * NCH1 * NBINS + f;
  float* cp = carry + (size_t)b * NCH1 * NBINS + f;
  for (int c = 0; c < NCH1; ++c) {
    *cp = v;
    v = fmaf(aL, v, *bcp);
    bcp += NBINS;
    cp += NBINS;
  }
}

// ---------------------------------------------------------------------------
// Kernel 3 (fused): EMA-normalize one (b, 64-frame chunk) tile into LDS
// (bf16), then MFMA GEMM vs melbT straight to out.
// ---------------------------------------------------------------------------
__global__ __launch_bounds__(256) void scan_gemm(const ushort_t* __restrict__ magb,
                                                 const float* __restrict__ alpha,
                                                 const float* __restrict__ carry,
                                                 const ushort_t* __restrict__ melbT,
                                                 float* __restrict__ out) {
  const int c = blockIdx.x, b = blockIdx.y;
  const int tid = threadIdx.x;
  const int t0 = c * CHG;
  const int nv = min(CHG, NFRAMES - t0);

  __shared__ __align__(16) ushort_t Ns[CHG][LDSW];

  // phase 1: EMA + normalize into LDS (carry at fine chunk u = 8c)
  const float* crow = carry + ((size_t)b * NCH1 + 8 * c) * NBINS;
  for (int f = tid; f < KPAD; f += 256) {
    if (f < NBINS) {
      const float a = sigmoidf_(alpha[f]);
      const float om = 1.0f - a;
      float v = crow[f];
      const ushort_t* p = magb + ((size_t)b * NFRAMES + t0) * NBINS + f;
      int t = 0;
      for (; t < nv; ++t) {
        float m = b2f(*p);
        v = fmaf(a, v, om * m);
        Ns[t][f] = f2b(m * __builtin_amdgcn_rcpf(v + 1e-8f));
        p += NBINS;
      }
      for (; t < CHG; ++t) Ns[t][f] = 0;
    } else {
      for (int t = 0; t < CHG; ++t) Ns[t][f] = 0;
    }
  }
  __syncthreads();

  // phase 2: (64 x 288) @ (288 x 64) via MFMA 16x16x32 bf16
  const int wave = tid >> 6, lane = tid & 63;
  const int m = lane & 15, quad = lane >> 4;
  const int r0 = wave * 16;

  f32x4 acc[4];
#pragma unroll
  for (int ct = 0; ct < 4; ++ct) acc[ct] = (f32x4){0.f, 0.f, 0.f, 0.f};

#pragma unroll
  for (int ks = 0; ks < 9; ++ks) {
    bf16x8 a = *(const bf16x8*)&Ns[r0 + m][ks * 32 + quad * 8];
#pragma unroll
    for (int ct = 0; ct < 4; ++ct) {
      bf16x8 bb = *(const bf16x8*)(melbT + (size_t)(ct * 16 + m) * KPAD + ks * 32 + quad * 8);
      acc[ct] = __builtin_amdgcn_mfma_f32_16x16x32_bf16(a, bb, acc[ct], 0, 0, 0);
    }
  }

#pragma unroll
  for (int ct = 0; ct < 4; ++ct) {
#pragma unroll
    for (int r = 0; r < 4; ++r) {
      int tl = r0 + quad * 4 + r;
      if (t0 + tl < NFRAMES)
        out[((size_t)b * NFRAMES + t0 + tl) * NMELS + ct * 16 + m] = acc[ct][r] + 1e-6f;
    }
  }
}

// ---------------------------------------------------------------------------
extern "C" void kernel_launch(void* const* d_in, const int* in_sizes, int n_in,
                              void* d_out, int out_size, void* d_ws, size_t ws_size,
                              hipStream_t stream) {
  const float* wav   = (const float*)d_in[0];
  const float* alpha = (const float*)d_in[1];
  const float* mel   = (const float*)d_in[2];
  float* out = (float*)d_out;

  // workspace layout
  ushort_t* magb  = (ushort_t*)d_ws;                          // 32*3751*257 bf16
  ushort_t* melbT = magb + (size_t)BATCH * NFRAMES * NBINS;   // 64*288 bf16
  float* Bc    = (float*)(melbT + (size_t)NMELS * KPAD);      // 32*469*257 f32
  float* carry = Bc + (size_t)BATCH * NCH1 * NBINS;           // 32*469*257 f32
  float* win   = carry + (size_t)BATCH * NCH1 * NBINS;        // 512
  float* twA   = win + 512;                                   // 1024
  float* twB   = twA + 1024;                                  // 128

  init_tables<<<1, 512, 0, stream>>>(mel, win, twA, twB, melbT);
  stft_scan<<<dim3(NCH1, BATCH), 64, 0, stream>>>(wav, win, twA, twB, alpha, magb, Bc);
  scan_combine<<<BATCH, 320, 0, stream>>>(magb, alpha, Bc, carry);
  scan_gemm<<<dim3(NCHG, BATCH), 256, 0, stream>>>(magb, alpha, carry, melbT, out);
}